// Round 16
// baseline (170.213 us; speedup 1.0000x reference)
//
#include <hip/hip_runtime.h>
#include <hip/hip_bf16.h>

#define NB   32
#define DIMK 512
#define MM   32
#define ZZ   64
#define MZV  2048
#define VOC  50257
#define NK4  1571                        // v-tiles of 32 (= k4z blocks)

typedef __attribute__((ext_vector_type(8)))  short  short8;   // 8 bf16
typedef __attribute__((ext_vector_type(4)))  float  f32x4;
typedef __attribute__((ext_vector_type(16))) float  f32x16;
typedef __attribute__((ext_vector_type(8)))  unsigned short ushort8;

// ws layout in floats
#define WS_W      0                       // [NB][MZV] raw scores (incl. log mask)
#define WS_PVEC   (WS_W + NB*MZV)         // [NB][MM][DIMK] partial weighted vecs
#define WS_LSTAT  (WS_PVEC + NB*MM*DIMK)  // [NB][MM][2] (max, sum)
#define WS_GSTATW (WS_LSTAT + NB*MM*2)    // [NB][2] global (max,sum) copy branch
#define WS_MIX    (WS_GSTATW + NB*2)      // [NB][2]
#define WS_GPART  (WS_MIX + NB*2)         // [NB][32][2] gen softmax partials

// pack 8 f32 -> 8 bf16 (RNE) via v_cvt_pk_bf16_f32 (compiler-generated)
__device__ __forceinline__ ushort8 cvt8(float4 a, float4 b) {
    union { ushort8 u; __hip_bfloat162 h[4]; } r;
    r.h[0] = __float22bfloat162_rn(make_float2(a.x, a.y));
    r.h[1] = __float22bfloat162_rn(make_float2(a.z, a.w));
    r.h[2] = __float22bfloat162_rn(make_float2(b.x, b.y));
    r.h[3] = __float22bfloat162_rn(make_float2(b.z, b.w));
    return r.u;
}

// Fused k1 (mem-branch attention) || k4z (zero-sync gen GEMM).
// Block-type dispatch (grid = 1024 k1 + 1571 k4z = 2595):
//   bid < 2048: even -> k1 (sub=bid>>1), odd -> k4z (sub=bid>>1)
//   bid >= 2048: k4z tail (sub=bid-1024)
//
// k4z: the ninth k4 design, and the first with ZERO block-level sync.
// Wave = one 32x32 v-tile (mfma_f32_32x32x16_bf16, all 32 batches in one
// 16-reg acc) x one K-quarter (256 f32). 4 waves/block = one v-tile's 4
// quarters; K-split partials atomicAdd into the pre-zeroed logits region of
// d_out. Per step each lane loads 8 f32 of W (2xfloat4; 16 lanes span 16
// 4KB-strided rows -> exactly 16x64B lines per instr, dense-optimal) and
// 8 f32 of h from L2-hot encsumm/enc, cvt_pk's to bf16, one MFMA. No LDS,
// no barriers, no vmcnt(0) drains -> pure per-wave pipelined stream.
__global__ __launch_bounds__(256, 6) void k14_fused(
    const float* __restrict__ enc, const float* __restrict__ embsumm,
    const float* __restrict__ encsumm,
    const float* __restrict__ memencs, const float* __restrict__ memembsumm,
    const float* __restrict__ memmask,
    const float* __restrict__ W_out, float* __restrict__ out,
    float* __restrict__ ws)
{
    __shared__ __align__(16) struct { float sacc[4][DIMK]; float sst[4][2]; } s1;

    int bid = blockIdx.x;
    int tid = threadIdx.x, wid = tid >> 6, lane = tid & 63;
    bool isK1; int sub;
    if (bid < 2048) { isK1 = ((bid & 1) == 0); sub = bid >> 1; }
    else            { isK1 = false;            sub = bid - 1024; }

    if (isK1) {
        // ================= k1: per (b,m) scores + online-softmax weighted sum =====
        int b = sub >> 5, m = sub & 31;
        int c0 = lane * 4, c1 = c0 + 256;
        const float* encb = enc + b * DIMK;
        const float* embb = embsumm + b * DIMK;
        float4 qe0 = *(const float4*)(encb + c0);
        float4 qe1 = *(const float4*)(encb + c1);
        float4 qm0 = *(const float4*)(embb + c0);
        float4 qm1 = *(const float4*)(embb + c1);
        const float* meb = memencs    + (long)(b*MM + m) * ZZ * DIMK;
        const float* mmb = memembsumm + (long)(b*MM + m) * ZZ * DIMK;
        const float* mkb = memmask    + (long)(b*MM + m) * ZZ;
        float* w_ws = ws + WS_W + b*MZV + m*ZZ;

        float lmax = -3.0e38f, lsum = 0.f;
        float4 a0 = make_float4(0.f,0.f,0.f,0.f), a1 = make_float4(0.f,0.f,0.f,0.f);

        for (int z = wid; z < ZZ; z += 4) {
            const float* mer = meb + z*DIMK;
            const float* mmr = mmb + z*DIMK;
            float4 e0 = *(const float4*)(mer + c0);
            float4 e1 = *(const float4*)(mer + c1);
            float4 s0 = *(const float4*)(mmr + c0);
            float4 s1v = *(const float4*)(mmr + c1);
            float d = e0.x*qe0.x + e0.y*qe0.y + e0.z*qe0.z + e0.w*qe0.w
                    + e1.x*qe1.x + e1.y*qe1.y + e1.z*qe1.z + e1.w*qe1.w
                    + s0.x*qm0.x + s0.y*qm0.y + s0.z*qm0.z + s0.w*qm0.w
                    + s1v.x*qm1.x + s1v.y*qm1.y + s1v.z*qm1.z + s1v.w*qm1.w;
            #pragma unroll
            for (int off = 32; off; off >>= 1) d += __shfl_xor(d, off);
            d += logf(mkb[z]);                 // mask=1 -> +0; mask=0 -> -inf
            if (lane == 0) w_ws[z] = d;
            float nm = fmaxf(lmax, d);
            float sc = __expf(lmax - nm);
            float e  = __expf(d - nm);
            lsum = lsum * sc + e;
            a0.x = a0.x*sc + e*e0.x; a0.y = a0.y*sc + e*e0.y;
            a0.z = a0.z*sc + e*e0.z; a0.w = a0.w*sc + e*e0.w;
            a1.x = a1.x*sc + e*e1.x; a1.y = a1.y*sc + e*e1.y;
            a1.z = a1.z*sc + e*e1.z; a1.w = a1.w*sc + e*e1.w;
            lmax = nm;
        }

        *(float4*)&s1.sacc[wid][c0] = a0;
        *(float4*)&s1.sacc[wid][c1] = a1;
        if (lane == 0) { s1.sst[wid][0] = lmax; s1.sst[wid][1] = lsum; }
        __syncthreads();
        float bm = fmaxf(fmaxf(s1.sst[0][0], s1.sst[1][0]),
                         fmaxf(s1.sst[2][0], s1.sst[3][0]));
        float sc0 = __expf(s1.sst[0][0]-bm), sc1 = __expf(s1.sst[1][0]-bm);
        float sc2 = __expf(s1.sst[2][0]-bm), sc3 = __expf(s1.sst[3][0]-bm);
        float bs = s1.sst[0][1]*sc0 + s1.sst[1][1]*sc1
                 + s1.sst[2][1]*sc2 + s1.sst[3][1]*sc3;
        int d0 = tid * 2;
        float2 v0 = *(float2*)&s1.sacc[0][d0];
        float2 v1 = *(float2*)&s1.sacc[1][d0];
        float2 v2 = *(float2*)&s1.sacc[2][d0];
        float2 v3 = *(float2*)&s1.sacc[3][d0];
        float p0 = v0.x*sc0 + v1.x*sc1 + v2.x*sc2 + v3.x*sc3;
        float p1 = v0.y*sc0 + v1.y*sc1 + v2.y*sc2 + v3.y*sc3;
        float* pv = ws + WS_PVEC + (long)(b*MM+m)*DIMK + d0;
        pv[0] = p0; pv[1] = p1;
        if (tid == 0) { float* ls = ws + WS_LSTAT + (b*MM+m)*2; ls[0] = bm; ls[1] = bs; }
    } else {
        // ================= k4z: zero-sync MFMA gen-GEMM ==========================
        // wave = v-tile 'sub' (32 vocab rows) x K-quarter 'wid' (256 f32)
        int vt = sub * 32;
        int kq = wid;                    // 0..3
        int rc = lane & 31;              // A row (batch) AND B col (vocab) index
        int kg = lane >> 5;              // k-group (0/1) within each K=16 step

        long wrow = min(vt + rc, VOC - 1);
        const float* wp = W_out + wrow*1024 + kq*256 + kg*8;
        const float* hp = (kq < 2 ? encsumm : enc) + rc*DIMK + (kq & 1)*256 + kg*8;

        f32x16 acc = {0.f,0.f,0.f,0.f,0.f,0.f,0.f,0.f,
                      0.f,0.f,0.f,0.f,0.f,0.f,0.f,0.f};

        #pragma unroll 4
        for (int s = 0; s < 16; ++s) {
            float4 ha0 = *(const float4*)(hp + s*16);
            float4 ha1 = *(const float4*)(hp + s*16 + 4);
            float4 wa0 = *(const float4*)(wp + s*16);
            float4 wa1 = *(const float4*)(wp + s*16 + 4);
            ushort8 au = cvt8(ha0, ha1);
            ushort8 wu = cvt8(wa0, wa1);
            acc = __builtin_amdgcn_mfma_f32_32x32x16_bf16(*(short8*)&au, *(short8*)&wu,
                                                          acc, 0, 0, 0);
        }

        // C/D 32x32 layout: col=lane&31, row=(reg&3)+8*(reg>>2)+4*(lane>>5)
        // (m74/m101-verified). row=batch m, col=v. K-split partial -> atomicAdd.
        int v = vt + rc;
        if (v < VOC) {
            #pragma unroll
            for (int r = 0; r < 16; ++r) {
                int m = (r & 3) + 8*(r >> 2) + 4*kg;
                atomicAdd(&out[(long)m*VOC + v], acc[r]);
            }
        }
    }
}

// Fused k2 (mem combine + mixer) || k5 (gen softmax partials over raw logits + bias):
//   bid < 32  -> k2 for b=bid
//   bid >= 32 -> k5 for b=(bid-32)>>5, chunk=(bid-32)&31
__global__ __launch_bounds__(256) void k2k5(
    const float* __restrict__ encsumm, const float* __restrict__ enc,
    const float* __restrict__ W_mix, const float* __restrict__ b_mix,
    const float* __restrict__ b_out, const float* __restrict__ unk,
    float* __restrict__ out, float* __restrict__ ws)
{
    int bid = blockIdx.x, tid = threadIdx.x;
    if (bid < 32) {
        int b = bid;
        const float* ls = ws + WS_LSTAT + b*MM*2;
        float gm = -3.0e38f;
        #pragma unroll
        for (int m = 0; m < MM; m++) gm = fmaxf(gm, ls[m*2]);
        float gs = 0.f;
        #pragma unroll
        for (int m = 0; m < MM; m++) gs += ls[m*2+1] * __expf(ls[m*2] - gm);
        if (tid == 0) { ws[WS_GSTATW + b*2] = gm; ws[WS_GSTATW + b*2 + 1] = gs; }
        float inv = 1.0f / gs;
        int d0 = tid * 2;
        float p0 = 0.f, p1 = 0.f;
        for (int m = 0; m < MM; m++) {
            float sc = __expf(ls[m*2] - gm);
            const float* pv = ws + WS_PVEC + (long)(b*MM+m)*DIMK + d0;
            p0 += pv[0]*sc; p1 += pv[1]*sc;
        }
        out[(long)NB*VOC + b*DIMK + d0]     = p0 * inv;
        out[(long)NB*VOC + b*DIMK + d0 + 1] = p1 * inv;

        if (tid < 64) {
            int l = tid;
            float m0 = 0.f, m1 = 0.f;
            #pragma unroll
            for (int p = 0; p < 4; p++) {
                int cc = l*4 + p*256;
                float4 h4 = (cc < 512) ? *(const float4*)(encsumm + b*DIMK + cc)
                                       : *(const float4*)(enc + b*DIMK + cc - 512);
                float4 w0 = *(const float4*)(W_mix + cc);
                float4 w1 = *(const float4*)(W_mix + 1024 + cc);
                m0 += h4.x*w0.x + h4.y*w0.y + h4.z*w0.z + h4.w*w0.w;
                m1 += h4.x*w1.x + h4.y*w1.y + h4.z*w1.z + h4.w*w1.w;
            }
            #pragma unroll
            for (int off = 32; off; off >>= 1) { m0 += __shfl_xor(m0, off); m1 += __shfl_xor(m1, off); }
            if (l == 0) {
                m0 += b_mix[0]; m1 += b_mix[1];
                float mx = fmaxf(m0, m1);
                float e0 = __expf(m0-mx), e1 = __expf(m1-mx);
                float s = e0 + e1;
                ws[WS_MIX + b*2] = e0/s; ws[WS_MIX + b*2 + 1] = e1/s;
            }
        }
    } else {
        int sub = bid - 32;
        int chunk = sub & 31, b = sub >> 5;
        const float* logits = out;
        const int CH = (VOC + 31) / 32;
        int v0 = chunk * CH;
        int v1 = min(VOC, v0 + CH);
        float m = -3.0e38f, s = 0.f;
        for (int v = v0 + tid; v < v1; v += 256) {
            float x = logits[(long)b*VOC + v] + b_out[v] + logf(unk[v]);
            float nm = fmaxf(m, x);
            s = s*__expf(m - nm) + __expf(x - nm);
            m = nm;
        }
        #pragma unroll
        for (int off = 32; off; off >>= 1) {
            float om = __shfl_xor(m, off), os = __shfl_xor(s, off);
            float nm = fmaxf(m, om);
            s = s*__expf(m - nm) + os*__expf(om - nm);
            m = nm;
        }
        __shared__ float sm[4], ssum[4];
        int wid = tid >> 6, lane = tid & 63;
        if (lane == 0) { sm[wid] = m; ssum[wid] = s; }
        __syncthreads();
        if (tid == 0) {
            float gm = fmaxf(fmaxf(sm[0], sm[1]), fmaxf(sm[2], sm[3]));
            float gs = ssum[0]*__expf(sm[0]-gm) + ssum[1]*__expf(sm[1]-gm)
                     + ssum[2]*__expf(sm[2]-gm) + ssum[3]*__expf(sm[3]-gm);
            ws[WS_GPART + (b*32 + chunk)*2]     = gm;
            ws[WS_GPART + (b*32 + chunk)*2 + 1] = gs;
        }
    }
}

// K6: probs = mix0 * softmax(raw_logits + bias), in place; merges chunk partials
__global__ __launch_bounds__(256) void k6_final(float* __restrict__ probs,
                                                const float* __restrict__ b_out,
                                                const float* __restrict__ unk,
                                                const float* __restrict__ ws)
{
    int v = blockIdx.x*256 + threadIdx.x;
    int b = blockIdx.y;
    float gm = -3.0e38f;
    #pragma unroll
    for (int i = 0; i < 32; ++i) gm = fmaxf(gm, ws[WS_GPART + (b*32+i)*2]);
    float gs = 0.f;
    #pragma unroll
    for (int i = 0; i < 32; ++i)
        gs += ws[WS_GPART + (b*32+i)*2 + 1] * __expf(ws[WS_GPART + (b*32+i)*2] - gm);
    if (v >= VOC) return;
    float mix0 = ws[WS_MIX + b*2];
    float bias = b_out[v] + logf(unk[v]);
    long idx = (long)b*VOC + v;
    probs[idx] = mix0 * __expf(probs[idx] + bias - gm) / gs;
}

// K7: copy-branch scatter: probs[b, tok] += mix1*alpha
__global__ __launch_bounds__(256) void k7_scatter(const int* __restrict__ memids,
                                                  const float* __restrict__ ws,
                                                  float* __restrict__ probs)
{
    int idx = blockIdx.x*256 + threadIdx.x;   // NB*MZV = 65536
    int b = idx >> 11, mz = idx & 2047;
    float gm = ws[WS_GSTATW + b*2], gs = ws[WS_GSTATW + b*2 + 1];
    float mix1 = ws[WS_MIX + b*2 + 1];
    float alpha = __expf(ws[WS_W + b*MZV + mz] - gm) / gs;
    int tok = memids[b*MZV + mz];
    atomicAdd(&probs[(long)b*VOC + tok], mix1 * alpha);
}

extern "C" void kernel_launch(void* const* d_in, const int* in_sizes, int n_in,
                              void* d_out, int out_size, void* d_ws, size_t ws_size,
                              hipStream_t stream)
{
    const float* enc        = (const float*)d_in[0];
    const float* encsumm    = (const float*)d_in[1];
    const float* embsumm    = (const float*)d_in[2];
    const float* memencs    = (const float*)d_in[3];
    // d_in[4] = memencsumm: provably unused (zeros in both concat middles)
    const float* memembsumm = (const float*)d_in[5];
    const float* memmask    = (const float*)d_in[6];
    const int*   memids     = (const int*)d_in[7];
    const float* W_out      = (const float*)d_in[8];
    const float* b_out      = (const float*)d_in[9];
    const float* W_mix      = (const float*)d_in[10];
    const float* b_mix      = (const float*)d_in[11];
    const float* unk        = (const float*)d_in[12];
    float* out = (float*)d_out;
    float* ws  = (float*)d_ws;

    // zero the logits-accumulation region (K-split partials atomicAdd into it)
    hipMemsetAsync(out, 0, (size_t)NB * VOC * sizeof(float), stream);

    hipLaunchKernelGGL(k14_fused, dim3(1024 + NK4), dim3(256), 0, stream,
                       enc, embsumm, encsumm, memencs, memembsumm, memmask,
                       W_out, out, ws);
    hipLaunchKernelGGL(k2k5, dim3(32 + 1024), dim3(256), 0, stream,
                       encsumm, enc, W_mix, b_mix, b_out, unk, out, ws);
    hipLaunchKernelGGL(k6_final, dim3((VOC + 255)/256, NB), dim3(256), 0, stream,
                       out, b_out, unk, ws);
    hipLaunchKernelGGL(k7_scatter, dim3(NB*MZV/256), dim3(256), 0, stream, memids, ws, out);
}

// Round 17
// 128.390 us; speedup vs baseline: 1.3258x; 1.3258x over previous
//
#include <hip/hip_runtime.h>
#include <hip/hip_bf16.h>

#define NB   32
#define DIMK 512
#define MM   32
#define ZZ   64
#define MZV  2048
#define VOC  50257
#define NK4  1571                        // (VOC+31)/32 k4-type blocks

typedef __attribute__((ext_vector_type(8))) short  short8;   // 8 bf16 = 4 VGPR
typedef __attribute__((ext_vector_type(4))) float  f32x4;
typedef __attribute__((ext_vector_type(8))) unsigned short ushort8;

// ws layout in floats
#define WS_W      0                       // [NB][MZV] raw scores (incl. log mask)
#define WS_PVEC   (WS_W + NB*MZV)         // [NB][MM][DIMK] partial weighted vecs
#define WS_LSTAT  (WS_PVEC + NB*MM*DIMK)  // [NB][MM][2] (max, sum)
#define WS_GSTATW (WS_LSTAT + NB*MM*2)    // [NB][2] global (max,sum) copy branch
#define WS_MIX    (WS_GSTATW + NB*2)      // [NB][2]
#define WS_GPART  (WS_MIX + NB*2)         // [NB][32][2] gen softmax partials

// pack 8 f32 -> 8 bf16 (RNE) via v_cvt_pk_bf16_f32 (compiler-generated)
__device__ __forceinline__ ushort8 cvt8(float4 a, float4 b) {
    union { ushort8 u; __hip_bfloat162 h[4]; } r;
    r.h[0] = __float22bfloat162_rn(make_float2(a.x, a.y));
    r.h[1] = __float22bfloat162_rn(make_float2(a.z, a.w));
    r.h[2] = __float22bfloat162_rn(make_float2(b.x, b.y));
    r.h[3] = __float22bfloat162_rn(make_float2(b.z, b.w));
    return r.u;
}

// async global -> LDS, 16B per lane (direct DMA, no VGPR round-trip)
typedef const __attribute__((address_space(1))) void* gas_t;
typedef __attribute__((address_space(3))) void*       las_t;
__device__ __forceinline__ void gload16(const void* g, void* l) {
    __builtin_amdgcn_global_load_lds((gas_t)g, (las_t)l, 16, 0, 0);
}

// Fused k1 (mem-branch attention) || k4 (gen GEMM). Block-type dispatch:
//   bid < 2048: even -> k1 (sub=bid>>1), odd -> k4 (sub=bid>>1)
//   bid >= 2048: k4 tail (sub=bid-1024); k4 total = 1571
// [FINAL: round-13/15 config, best measured 128.2 µs. Nine k4 designs probed
// (reg-staged x3, DMA, tile sizes, occupancy, channel-rotation, counted-vmcnt,
// zero-sync atomics): all 62-66 µs or worse -> schedule-invariant floor.]
__global__ __launch_bounds__(256, 6) void k14_fused(
    const float* __restrict__ enc, const float* __restrict__ embsumm,
    const float* __restrict__ encsumm,
    const float* __restrict__ memencs, const float* __restrict__ memembsumm,
    const float* __restrict__ memmask,
    const float* __restrict__ W_out, const float* __restrict__ b_out,
    const float* __restrict__ unk, float* __restrict__ out,
    float* __restrict__ ws)
{
    __shared__ __align__(16) union {
        struct { float sacc[4][DIMK]; float sst[4][2]; } s1;         // 8.03 KB
        struct { float w[2][2048]; unsigned short a[2][2048]; } s4;  // 16 + 8 KB
    } smem;

    int bid = blockIdx.x;
    int tid = threadIdx.x, wid = tid >> 6, lane = tid & 63;
    bool isK1; int sub;
    if (bid < 2048) { isK1 = ((bid & 1) == 0); sub = bid >> 1; }
    else            { isK1 = false;            sub = bid - 1024; }

    if (isK1) {
        // ================= k1: per (b,m) scores + online-softmax weighted sum =====
        int b = sub >> 5, m = sub & 31;
        int c0 = lane * 4, c1 = c0 + 256;
        const float* encb = enc + b * DIMK;
        const float* embb = embsumm + b * DIMK;
        float4 qe0 = *(const float4*)(encb + c0);
        float4 qe1 = *(const float4*)(encb + c1);
        float4 qm0 = *(const float4*)(embb + c0);
        float4 qm1 = *(const float4*)(embb + c1);
        const float* meb = memencs    + (long)(b*MM + m) * ZZ * DIMK;
        const float* mmb = memembsumm + (long)(b*MM + m) * ZZ * DIMK;
        const float* mkb = memmask    + (long)(b*MM + m) * ZZ;
        float* w_ws = ws + WS_W + b*MZV + m*ZZ;

        float lmax = -3.0e38f, lsum = 0.f;
        float4 a0 = make_float4(0.f,0.f,0.f,0.f), a1 = make_float4(0.f,0.f,0.f,0.f);

        for (int z = wid; z < ZZ; z += 4) {
            const float* mer = meb + z*DIMK;
            const float* mmr = mmb + z*DIMK;
            float4 e0 = *(const float4*)(mer + c0);
            float4 e1 = *(const float4*)(mer + c1);
            float4 s0 = *(const float4*)(mmr + c0);
            float4 s1 = *(const float4*)(mmr + c1);
            float d = e0.x*qe0.x + e0.y*qe0.y + e0.z*qe0.z + e0.w*qe0.w
                    + e1.x*qe1.x + e1.y*qe1.y + e1.z*qe1.z + e1.w*qe1.w
                    + s0.x*qm0.x + s0.y*qm0.y + s0.z*qm0.z + s0.w*qm0.w
                    + s1.x*qm1.x + s1.y*qm1.y + s1.z*qm1.z + s1.w*qm1.w;
            #pragma unroll
            for (int off = 32; off; off >>= 1) d += __shfl_xor(d, off);
            d += logf(mkb[z]);                 // mask=1 -> +0; mask=0 -> -inf
            if (lane == 0) w_ws[z] = d;
            float nm = fmaxf(lmax, d);
            float sc = __expf(lmax - nm);
            float e  = __expf(d - nm);
            lsum = lsum * sc + e;
            a0.x = a0.x*sc + e*e0.x; a0.y = a0.y*sc + e*e0.y;
            a0.z = a0.z*sc + e*e0.z; a0.w = a0.w*sc + e*e0.w;
            a1.x = a1.x*sc + e*e1.x; a1.y = a1.y*sc + e*e1.y;
            a1.z = a1.z*sc + e*e1.z; a1.w = a1.w*sc + e*e1.w;
            lmax = nm;
        }

        *(float4*)&smem.s1.sacc[wid][c0] = a0;
        *(float4*)&smem.s1.sacc[wid][c1] = a1;
        if (lane == 0) { smem.s1.sst[wid][0] = lmax; smem.s1.sst[wid][1] = lsum; }
        __syncthreads();
        float bm = fmaxf(fmaxf(smem.s1.sst[0][0], smem.s1.sst[1][0]),
                         fmaxf(smem.s1.sst[2][0], smem.s1.sst[3][0]));
        float sc0 = __expf(smem.s1.sst[0][0]-bm), sc1 = __expf(smem.s1.sst[1][0]-bm);
        float sc2 = __expf(smem.s1.sst[2][0]-bm), sc3 = __expf(smem.s1.sst[3][0]-bm);
        float bs = smem.s1.sst[0][1]*sc0 + smem.s1.sst[1][1]*sc1
                 + smem.s1.sst[2][1]*sc2 + smem.s1.sst[3][1]*sc3;
        int d0 = tid * 2;
        float2 v0 = *(float2*)&smem.s1.sacc[0][d0];
        float2 v1 = *(float2*)&smem.s1.sacc[1][d0];
        float2 v2 = *(float2*)&smem.s1.sacc[2][d0];
        float2 v3 = *(float2*)&smem.s1.sacc[3][d0];
        float p0 = v0.x*sc0 + v1.x*sc1 + v2.x*sc2 + v3.x*sc3;
        float p1 = v0.y*sc0 + v1.y*sc1 + v2.y*sc2 + v3.y*sc3;
        float* pv = ws + WS_PVEC + (long)(b*MM+m)*DIMK + d0;
        pv[0] = p0; pv[1] = p1;
        if (tid == 0) { float* ls = ws + WS_LSTAT + (b*MM+m)*2; ls[0] = bm; ls[1] = bs; }
    } else {
        // ================= k4: MFMA gen-GEMM tile (32 v x 32 b) ===================
        int wv = wid >> 1, wb = wid & 1;
        int vt = sub * 32;

        // W staging (DMA, source-swizzled): slot idx -> row=idx>>4, q=idx&15
        int idx0 = (wid*2 + 0)*64 + lane;
        int idx1 = (wid*2 + 1)*64 + lane;
        int wr0 = idx0 >> 4, wq0 = idx0 & 15;
        int wr1 = idx1 >> 4, wq1 = idx1 & 15;
        const float* wsrc0 = W_out + (long)min(vt + wr0, VOC-1)*1024 + ((wq0 ^ (wr0 & 7))*4);
        const float* wsrc1 = W_out + (long)min(vt + wr1, VOC-1)*1024 + ((wq1 ^ (wr1 & 7))*4);
        // A staging (reg + cvt, from L2-resident encsumm/enc): row ar, granule ag
        int ar = tid >> 3, ag = tid & 7;
        const float* hs0 = encsumm + ar*DIMK + ag*8;    // chunks 0..7
        const float* hs1 = enc     + ar*DIMK + ag*8;    // chunks 8..15
        int awpos = ar*64 + ((ag ^ (ar & 7))*8);

        int ph = sub & 15;                 // per-block k-phase rotation

#define PC(c) (((c) + ph) & 15)
#define ISSUE_W(pc, buf) do {                                         \
            gload16(wsrc0 + (pc)*64, &smem.s4.w[buf][idx0*4]);        \
            gload16(wsrc1 + (pc)*64, &smem.s4.w[buf][idx1*4]); } while (0)
#define LOADA(pc) do { const float* hp = ((pc) < 8 ? hs0 + (pc)*64 : hs1 + ((pc)-8)*64); \
            af0 = *(const float4*)(hp); af1 = *(const float4*)(hp + 4); } while (0)
#define WRITEA(buf) do { *(ushort8*)&smem.s4.a[buf][awpos] = cvt8(af0, af1); } while (0)

        int lg = lane >> 4, ln = lane & 15;
        int vrow = wv*16 + ln;            // B-operand column (vocab row)
        int ab   = wb*16 + ln;            // A-operand row (batch)
        f32x4 acc = {0.f, 0.f, 0.f, 0.f};
        float4 af0, af1;

        LOADA(PC(0)); WRITEA(0);
        LOADA(PC(1)); WRITEA(1);
        LOADA(PC(2));                      // stashed for c=0 iteration
        ISSUE_W(PC(0), 0);
        ISSUE_W(PC(1), 1);
        __syncthreads();                   // drains A writes + W DMA for 0,1

        for (int c = 0; c < 16; ++c) {
            int buf = c & 1;
            #pragma unroll
            for (int s = 0; s < 2; ++s) {
                int q = s*8 + lg*2;
                float4 b0 = *(const float4*)&smem.s4.w[buf][vrow*64 + ((q    ) ^ (vrow & 7))*4];
                float4 b1 = *(const float4*)&smem.s4.w[buf][vrow*64 + ((q + 1) ^ (vrow & 7))*4];
                int g = s*4 + lg;
                short8 afrag = *(const short8*)&smem.s4.a[buf][ab*64 + ((g ^ (ab & 7)))*8];
                ushort8 bu = cvt8(b0, b1);
                short8 bfrag = *(short8*)&bu;
                acc = __builtin_amdgcn_mfma_f32_16x16x32_bf16(afrag, bfrag, acc, 0, 0, 0);
            }
            __syncthreads();               // everyone done with buf
            if (c + 2 < 16) {
                WRITEA(buf);               // chunk PC(c+2) content (loaded last iter)
                ISSUE_W(PC(c + 2), buf);   // in flight across compute(c+1)
                if (c + 3 < 16) LOADA(PC(c + 3));
            }
        }
#undef PC
#undef ISSUE_W
#undef LOADA
#undef WRITEA

        int v = vt + vrow;
        if (v < VOC) {
            float bias = b_out[v] + logf(unk[v]);
            #pragma unroll
            for (int rr = 0; rr < 4; ++rr) {
                int m = wb*16 + lg*4 + rr;
                out[(long)m*VOC + v] = acc[rr] + bias;
            }
        }
    }
}

// Fused k2 (mem combine + mixer) || k5 (gen softmax partials):
//   bid < 32  -> k2 for b=bid
//   bid >= 32 -> k5 for b=(bid-32)>>5, chunk=(bid-32)&31
__global__ __launch_bounds__(256) void k2k5(
    const float* __restrict__ encsumm, const float* __restrict__ enc,
    const float* __restrict__ W_mix, const float* __restrict__ b_mix,
    float* __restrict__ out, float* __restrict__ ws)
{
    int bid = blockIdx.x, tid = threadIdx.x;
    if (bid < 32) {
        int b = bid;
        const float* ls = ws + WS_LSTAT + b*MM*2;
        float gm = -3.0e38f;
        #pragma unroll
        for (int m = 0; m < MM; m++) gm = fmaxf(gm, ls[m*2]);
        float gs = 0.f;
        #pragma unroll
        for (int m = 0; m < MM; m++) gs += ls[m*2+1] * __expf(ls[m*2] - gm);
        if (tid == 0) { ws[WS_GSTATW + b*2] = gm; ws[WS_GSTATW + b*2 + 1] = gs; }
        float inv = 1.0f / gs;
        int d0 = tid * 2;
        float p0 = 0.f, p1 = 0.f;
        for (int m = 0; m < MM; m++) {
            float sc = __expf(ls[m*2] - gm);
            const float* pv = ws + WS_PVEC + (long)(b*MM+m)*DIMK + d0;
            p0 += pv[0]*sc; p1 += pv[1]*sc;
        }
        out[(long)NB*VOC + b*DIMK + d0]     = p0 * inv;
        out[(long)NB*VOC + b*DIMK + d0 + 1] = p1 * inv;

        if (tid < 64) {
            int l = tid;
            float m0 = 0.f, m1 = 0.f;
            #pragma unroll
            for (int p = 0; p < 4; p++) {
                int cc = l*4 + p*256;
                float4 h4 = (cc < 512) ? *(const float4*)(encsumm + b*DIMK + cc)
                                       : *(const float4*)(enc + b*DIMK + cc - 512);
                float4 w0 = *(const float4*)(W_mix + cc);
                float4 w1 = *(const float4*)(W_mix + 1024 + cc);
                m0 += h4.x*w0.x + h4.y*w0.y + h4.z*w0.z + h4.w*w0.w;
                m1 += h4.x*w1.x + h4.y*w1.y + h4.z*w1.z + h4.w*w1.w;
            }
            #pragma unroll
            for (int off = 32; off; off >>= 1) { m0 += __shfl_xor(m0, off); m1 += __shfl_xor(m1, off); }
            if (l == 0) {
                m0 += b_mix[0]; m1 += b_mix[1];
                float mx = fmaxf(m0, m1);
                float e0 = __expf(m0-mx), e1 = __expf(m1-mx);
                float s = e0 + e1;
                ws[WS_MIX + b*2] = e0/s; ws[WS_MIX + b*2 + 1] = e1/s;
            }
        }
    } else {
        int sub = bid - 32;
        int chunk = sub & 31, b = sub >> 5;
        const float* logits = out;
        const int CH = (VOC + 31) / 32;
        int v0 = chunk * CH;
        int v1 = min(VOC, v0 + CH);
        float m = -3.0e38f, s = 0.f;
        for (int v = v0 + tid; v < v1; v += 256) {
            float x = logits[(long)b*VOC + v];
            float nm = fmaxf(m, x);
            s = s*__expf(m - nm) + __expf(x - nm);
            m = nm;
        }
        #pragma unroll
        for (int off = 32; off; off >>= 1) {
            float om = __shfl_xor(m, off), os = __shfl_xor(s, off);
            float nm = fmaxf(m, om);
            s = s*__expf(m - nm) + os*__expf(om - nm);
            m = nm;
        }
        __shared__ float sm[4], ssum[4];
        int wid = tid >> 6, lane = tid & 63;
        if (lane == 0) { sm[wid] = m; ssum[wid] = s; }
        __syncthreads();
        if (tid == 0) {
            float gm = fmaxf(fmaxf(sm[0], sm[1]), fmaxf(sm[2], sm[3]));
            float gs = ssum[0]*__expf(sm[0]-gm) + ssum[1]*__expf(sm[1]-gm)
                     + ssum[2]*__expf(sm[2]-gm) + ssum[3]*__expf(sm[3]-gm);
            ws[WS_GPART + (b*32 + chunk)*2]     = gm;
            ws[WS_GPART + (b*32 + chunk)*2 + 1] = gs;
        }
    }
}

// K6: probs = mix0 * softmax(logits), in place; merges the 32 chunk partials inline
__global__ __launch_bounds__(256) void k6_final(float* __restrict__ probs, const float* __restrict__ ws)
{
    int v = blockIdx.x*256 + threadIdx.x;
    int b = blockIdx.y;
    float gm = -3.0e38f;
    #pragma unroll
    for (int i = 0; i < 32; ++i) gm = fmaxf(gm, ws[WS_GPART + (b*32+i)*2]);
    float gs = 0.f;
    #pragma unroll
    for (int i = 0; i < 32; ++i)
        gs += ws[WS_GPART + (b*32+i)*2 + 1] * __expf(ws[WS_GPART + (b*32+i)*2] - gm);
    if (v >= VOC) return;
    float mix0 = ws[WS_MIX + b*2];
    long idx = (long)b*VOC + v;
    probs[idx] = mix0 * __expf(probs[idx] - gm) / gs;
}

// K7: copy-branch scatter: probs[b, tok] += mix1*alpha
__global__ __launch_bounds__(256) void k7_scatter(const int* __restrict__ memids,
                                                  const float* __restrict__ ws,
                                                  float* __restrict__ probs)
{
    int idx = blockIdx.x*256 + threadIdx.x;   // NB*MZV = 65536
    int b = idx >> 11, mz = idx & 2047;
    float gm = ws[WS_GSTATW + b*2], gs = ws[WS_GSTATW + b*2 + 1];
    float mix1 = ws[WS_MIX + b*2 + 1];
    float alpha = __expf(ws[WS_W + b*MZV + mz] - gm) / gs;
    int tok = memids[b*MZV + mz];
    atomicAdd(&probs[(long)b*VOC + tok], mix1 * alpha);
}

extern "C" void kernel_launch(void* const* d_in, const int* in_sizes, int n_in,
                              void* d_out, int out_size, void* d_ws, size_t ws_size,
                              hipStream_t stream)
{
    const float* enc        = (const float*)d_in[0];
    const float* encsumm    = (const float*)d_in[1];
    const float* embsumm    = (const float*)d_in[2];
    const float* memencs    = (const float*)d_in[3];
    // d_in[4] = memencsumm: provably unused (zeros in both concat middles)
    const float* memembsumm = (const float*)d_in[5];
    const float* memmask    = (const float*)d_in[6];
    const int*   memids     = (const int*)d_in[7];
    const float* W_out      = (const float*)d_in[8];
    const float* b_out      = (const float*)d_in[9];
    const float* W_mix      = (const float*)d_in[10];
    const float* b_mix      = (const float*)d_in[11];
    const float* unk        = (const float*)d_in[12];
    float* out = (float*)d_out;
    float* ws  = (float*)d_ws;

    hipLaunchKernelGGL(k14_fused, dim3(1024 + NK4), dim3(256), 0, stream,
                       enc, embsumm, encsumm, memencs, memembsumm, memmask,
                       W_out, b_out, unk, out, ws);
    hipLaunchKernelGGL(k2k5, dim3(32 + 1024), dim3(256), 0, stream,
                       encsumm, enc, W_mix, b_mix, out, ws);
    hipLaunchKernelGGL(k6_final, dim3((VOC + 255)/256, NB), dim3(256), 0, stream, out, ws);
    hipLaunchKernelGGL(k7_scatter, dim3(NB*MZV/256), dim3(256), 0, stream, memids, ws, out);
}